// Round 10
// baseline (4542.698 us; speedup 1.0000x reference)
//
#include <hip/hip_runtime.h>
#include <hip/hip_bf16.h>

#define T_LEN  1024
#define BATCH  64
#define HDIM   512
#define G4     2048

typedef __attribute__((ext_vector_type(8))) short short8;
typedef __attribute__((ext_vector_type(4))) float f32x4;
typedef __attribute__((ext_vector_type(4))) unsigned int u32x4;
typedef __hip_bfloat16 bf16;

__device__ __forceinline__ unsigned short bfbits(float f) {
    bf16 h = __float2bfloat16(f);
    return __builtin_bit_cast(unsigned short, h);
}
__device__ __forceinline__ float fsigmoid(float x) { return 1.f / (1.f + __expf(-x)); }
__device__ __forceinline__ float ftanh(float x)    { return 2.f / (1.f + __expf(-2.f * x)) - 1.f; }

// ---------------------------------------------------------------------------
// Kernel 1: convert weights to bf16, combine biases.
// ---------------------------------------------------------------------------
__global__ void conv_weights(const float* __restrict__ wihf, const float* __restrict__ whhf,
                             const float* __restrict__ bihf, const float* __restrict__ bhhf,
                             const float* __restrict__ wihb, const float* __restrict__ whhb,
                             const float* __restrict__ bihb, const float* __restrict__ bhhb,
                             bf16* __restrict__ wih, bf16* __restrict__ whh,
                             float* __restrict__ bias)
{
    int i = blockIdx.x * 256 + threadIdx.x;      // 0 .. 2*2048*512-1
    const int n1 = G4 * HDIM;
    if (i < n1) {
        wih[i] = __float2bfloat16(wihf[i]);
        whh[i] = __float2bfloat16(whhf[i]);
    } else {
        int k = i - n1;
        wih[n1 + k] = __float2bfloat16(wihb[k]);
        whh[n1 + k] = __float2bfloat16(whhb[k]);
    }
    if (i < G4)          bias[i] = bihf[i] + bhhf[i];
    else if (i < 2 * G4) bias[i] = bihb[i - G4] + bhhb[i - G4];
}

// ---------------------------------------------------------------------------
// Kernel 2: convert x to bf16 (identical content every replay -> stale-safe)
// ---------------------------------------------------------------------------
__global__ void conv_x(const float* __restrict__ x, bf16* __restrict__ xb)
{
    size_t i = (size_t)blockIdx.x * 256 + threadIdx.x;   // octet id
    const float* s = x + i * 8;
    float4 a = *reinterpret_cast<const float4*>(s);
    float4 b = *reinterpret_cast<const float4*>(s + 4);
    union { unsigned short us[8]; u32x4 v; } p;
    p.us[0] = bfbits(a.x); p.us[1] = bfbits(a.y); p.us[2] = bfbits(a.z); p.us[3] = bfbits(a.w);
    p.us[4] = bfbits(b.x); p.us[5] = bfbits(b.y); p.us[6] = bfbits(b.z); p.us[7] = bfbits(b.w);
    *reinterpret_cast<u32x4*>(xb + i * 8) = p.v;
}

// ---------------------------------------------------------------------------
// Kernel 3: zero sync words only (system scope, cross-dispatch-proven path).
// No data state crosses dispatches anymore: h0/c0 are read from d_in inside
// lstm_full, and hbuf is purely intra-dispatch (every slot written before read).
// ---------------------------------------------------------------------------
__global__ void init_sync(unsigned* __restrict__ flags, unsigned* __restrict__ xcdarr,
                          unsigned* __restrict__ abortw)
{
    int i = threadIdx.x;                         // single block of 256
    __hip_atomic_store(&flags[i],  0u, __ATOMIC_RELAXED, __HIP_MEMORY_SCOPE_SYSTEM);
    __hip_atomic_store(&xcdarr[i], 0u, __ATOMIC_RELAXED, __HIP_MEMORY_SCOPE_SYSTEM);
    if (i == 0) __hip_atomic_store(abortw, 0u, __ATOMIC_RELAXED, __HIP_MEMORY_SCOPE_SYSTEM);
}

// ---------------------------------------------------------------------------
// Kernel 4: full 1024-step recurrence. r9 compute core (call-1-proven:
// weights in per-wave VGPR frags, direct-register h loads + rule-#18 fence,
// 3 barriers) with two hardening changes:
//  (1) fast-path h stores / token publishes / flag zeroing use
//      __hip_atomic_exchange (workgroup scope): atomics execute AT the XCD
//      L2, so vmcnt retirement == L2 visibility for the consumers' sc0 loads
//      (plain workgroup stores carried no such cross-CU guarantee).
//  (2) zero cross-dispatch data state: h0/c0 read from d_in at t=0; no cbuf;
//      hbuf never read before written within the dispatch.
// Placement verify + team-uniform decision + system-scope fallback verbatim
// from round 4.
// ---------------------------------------------------------------------------
__global__ __launch_bounds__(256, 1) void lstm_full(
        const bf16* __restrict__ xb,        // [T][B][512] bf16
        const bf16* __restrict__ wih,       // [2][2048][512] bf16
        const bf16* __restrict__ whh,       // [2][2048][512] bf16
        const float* __restrict__ bias,     // [2][2048]
        const int*  __restrict__ lengths,   // [64]
        const float* __restrict__ h0f, const float* __restrict__ c0f,
        const float* __restrict__ h0b, const float* __restrict__ c0b,
        bf16*       __restrict__ hbuf,      // [2 parity][2 dir][B][H] bf16 (scratch)
        float*      __restrict__ out,       // [T][B][1024] fp32
        unsigned*   __restrict__ flags,     // [8*32]
        unsigned*   __restrict__ xcdarr,    // [256]
        unsigned*   __restrict__ abortw)    // [1]
{
    __shared__ float Gl[16][68];            // gate exchange
    __shared__ int ok_sh;
    __shared__ char lds_pad[100000];        // force 1 block/CU

    const int tid  = threadIdx.x;
    const int team = (int)blockIdx.x & 7;
    const int rank = (int)blockIdx.x >> 3;
    const int dir  = team >> 2;
    const int b0   = (team & 3) * 16;
    const int u0   = rank * 16;
    const int lane = tid & 63;
    const int w    = tid >> 6;              // wave = gate index 0..3
    const int uu   = lane & 15;             // matrix row/col within 16
    const int q    = lane >> 4;             // k-subchunk / C row group

    ((volatile char*)lds_pad)[tid] = 1;     // keep pad alive

    // phase 1: publish my XCD id (value 1..16)
    if (tid == 0) {
        unsigned xcc;
        asm volatile("s_getreg_b32 %0, hwreg(20, 0, 32)" : "=s"(xcc));
        __hip_atomic_store(&xcdarr[blockIdx.x], (xcc & 0xFu) + 1u,
                           __ATOMIC_RELAXED, __HIP_MEMORY_SCOPE_SYSTEM);
    }

    // phase 2: rank 0 verifies placement, zeroes team flags AT the team L2
    // (atomic exchange), publishes the team-uniform decision; others wait.
    if (rank == 0) {
        if (w == 0) {
            int idx = (lane < 32) ? (team + lane * 8) : ((team ^ 1) + (lane - 32) * 8);
            const unsigned* p = xcdarr + idx;
            unsigned v = 0, cnt = 0; int timeout = 0;
            for (;;) {
                v = __hip_atomic_load(p, __ATOMIC_RELAXED, __HIP_MEMORY_SCOPE_SYSTEM);
                if (__all((int)((v & 31u) != 0u))) break;
                if (++cnt > (1u << 20)) { timeout = 1; break; }
            }
            unsigned my = (unsigned)__shfl((int)(v & 31u), 0);
            int ok = (!timeout) &&
                     __all(lane < 32 ? (int)((v & 31u) == my) : (int)((v & 31u) != my));
            if (ok && lane < 32) {
                unsigned old = __hip_atomic_exchange(&flags[team * 32 + lane], 0u,
                                   __ATOMIC_RELAXED, __HIP_MEMORY_SCOPE_WORKGROUP);
                (void)old;
            }
            asm volatile("s_waitcnt vmcnt(0)" ::: "memory");   // zeros at L2
            if (lane == 0) {
                unsigned pub = my | 32u | (ok ? 64u : 0u);
                __hip_atomic_store(&xcdarr[blockIdx.x], pub,
                                   __ATOMIC_RELAXED, __HIP_MEMORY_SCOPE_SYSTEM);
                ok_sh = ok;
            }
        }
    } else {
        if (tid == 0) {
            const unsigned* p = xcdarr + team;
            unsigned v, cnt = 0;
            for (;;) {
                v = __hip_atomic_load(p, __ATOMIC_RELAXED, __HIP_MEMORY_SCOPE_SYSTEM);
                if (v & 32u) break;
                if (++cnt > (1u << 24)) { v = 32u; break; }   // bounded: fallback
            }
            ok_sh = (int)((v >> 6) & 1u);
        }
    }

    // per-wave weight fragments: wave w owns gate w, units u0..u0+15.
    short8 BI[16], BH[16];
    {
        const size_t grow = (size_t)(w * HDIM + u0 + uu);
        const bf16* wi = wih + (size_t)dir * G4 * HDIM + grow * HDIM + q * 8;
        const bf16* wh = whh + (size_t)dir * G4 * HDIM + grow * HDIM + q * 8;
#pragma unroll
        for (int ks = 0; ks < 16; ++ks) {
            BI[ks] = *reinterpret_cast<const short8*>(wi + ks * 32);
            BH[ks] = *reinterpret_cast<const short8*>(wh + ks * 32);
        }
    }
    const float bs = bias[dir * G4 + w * HDIM + u0 + uu];

    // pointwise ownership: thread (bb, cu) owns cell (b0+bb, u0+cu)
    const int bb = tid >> 4;
    const int cu = tid & 15;
    const int b_glob = b0 + bb;
    const int Lb = lengths[b_glob];
    // c0 straight from d_in (replay-invariant, never written by us)
    float c_reg = (dir ? c0b : c0f)[(size_t)b_glob * HDIM + u0 + cu];

    const int LA = lengths[b0 + uu];        // per-lane A-row flip length

    const unsigned* pollp = flags + team * 32 + (lane & 31);
    unsigned* flagw = flags + team * 32 + rank;

    __syncthreads();                        // ok_sh valid; weights loaded
    const bool fast = (ok_sh != 0);
    int dead = 0;

    // preload x A-frags for t = 0
    u32x4 A[16];
    {
        int st = 0; if (dir) st = (0 < LA) ? (LA - 1) : 0;
        const bf16* xp = xb + ((size_t)st * BATCH + b0 + uu) * HDIM + q * 8;
#pragma unroll
        for (int ks = 0; ks < 16; ++ks)
            A[ks] = *reinterpret_cast<const u32x4*>(xp + ks * 32);
    }

    for (int t = 0; t < T_LEN; ++t) {
        const int p = t & 1;

        // --- x-pass from prefetched registers (acc init = bias) ---
        f32x4 accx = f32x4{bs, bs, bs, bs};
#pragma unroll
        for (int ks = 0; ks < 16; ++ks)
            accx = __builtin_amdgcn_mfma_f32_16x16x32_bf16(
                __builtin_bit_cast(short8, A[ks]), BI[ks], accx, 0, 0, 0);

        // --- wait for h_t tokens: wave 0 only (load+waitcnt in ONE asm) ---
        if (w == 0 && t > 0 && !dead) {
            unsigned token = (unsigned)t, v, cnt = 0;
            if (fast) {
                for (;;) {
                    asm volatile("global_load_dword %0, %1, off sc0\n\ts_waitcnt vmcnt(0)"
                                 : "=v"(v) : "v"(pollp) : "memory");
                    if (__all((int)(v >= token))) break;
                    if (((++cnt) & 4095u) == 0) {
                        if (__hip_atomic_load(abortw, __ATOMIC_RELAXED, __HIP_MEMORY_SCOPE_SYSTEM)) { dead = 1; break; }
                        if (cnt > (1u << 22)) {
                            __hip_atomic_store(abortw, 1u, __ATOMIC_RELAXED, __HIP_MEMORY_SCOPE_SYSTEM);
                            dead = 1; break;
                        }
                    }
                }
            } else {
                for (;;) {
                    v = __hip_atomic_load(pollp, __ATOMIC_RELAXED, __HIP_MEMORY_SCOPE_SYSTEM);
                    if (__all((int)(v >= token))) break;
                    if (((++cnt) & 4095u) == 0) {
                        if (__hip_atomic_load(abortw, __ATOMIC_RELAXED, __HIP_MEMORY_SCOPE_SYSTEM)) { dead = 1; break; }
                        if (cnt > (1u << 22)) {
                            __hip_atomic_store(abortw, 1u, __ATOMIC_RELAXED, __HIP_MEMORY_SCOPE_SYSTEM);
                            dead = 1; break;
                        }
                    }
                }
            }
        }
        __syncthreads();   // B1: h published + poll complete before any h read

        // --- h_t -> A-frags ---
        u32x4 H[16];
        if (t == 0) {
            // h0 straight from d_in (fp32 -> bf16 frags); replay-invariant
            const float* h0p = (dir ? h0b : h0f) + (size_t)(b0 + uu) * HDIM;
#pragma unroll
            for (int ks = 0; ks < 16; ++ks) {
                const float* s = h0p + ks * 32 + q * 8;
                float4 f0 = *reinterpret_cast<const float4*>(s);
                float4 f1 = *reinterpret_cast<const float4*>(s + 4);
                union { unsigned short us[8]; u32x4 v; } pk;
                pk.us[0] = bfbits(f0.x); pk.us[1] = bfbits(f0.y);
                pk.us[2] = bfbits(f0.z); pk.us[3] = bfbits(f0.w);
                pk.us[4] = bfbits(f1.x); pk.us[5] = bfbits(f1.y);
                pk.us[6] = bfbits(f1.z); pk.us[7] = bfbits(f1.w);
                H[ks] = pk.v;
            }
        } else {
            const bf16* hb = hbuf + (size_t)(p * 2 + dir) * (BATCH * HDIM)
                                  + (size_t)(b0 + uu) * HDIM + q * 8;
            if (fast) {
#pragma unroll
                for (int ks = 0; ks < 16; ++ks)
                    asm volatile("global_load_dwordx4 %0, %1, off sc0"
                                 : "=v"(H[ks]) : "v"(hb + ks * 32) : "memory");
                asm volatile("s_waitcnt vmcnt(0)" ::: "memory");
                __builtin_amdgcn_sched_barrier(0);   // rule-#18 fence (r9-proven)
            } else {
#pragma unroll
                for (int ks = 0; ks < 16; ++ks) {
                    union { unsigned long long qv[2]; u32x4 v; } pk;
                    pk.qv[0] = __hip_atomic_load(
                        reinterpret_cast<const unsigned long long*>(hb + ks * 32),
                        __ATOMIC_RELAXED, __HIP_MEMORY_SCOPE_SYSTEM);
                    pk.qv[1] = __hip_atomic_load(
                        reinterpret_cast<const unsigned long long*>(hb + ks * 32 + 4),
                        __ATOMIC_RELAXED, __HIP_MEMORY_SCOPE_SYSTEM);
                    H[ks] = pk.v;
                }
            }
        }

        // --- h-pass, 2 independent 8-deep MFMA chains ---
        f32x4 acch0 = f32x4{0.f, 0.f, 0.f, 0.f};
        f32x4 acch1 = f32x4{0.f, 0.f, 0.f, 0.f};
#pragma unroll
        for (int ks = 0; ks < 8; ++ks) {
            acch0 = __builtin_amdgcn_mfma_f32_16x16x32_bf16(
                __builtin_bit_cast(short8, H[2 * ks]),     BH[2 * ks],     acch0, 0, 0, 0);
            acch1 = __builtin_amdgcn_mfma_f32_16x16x32_bf16(
                __builtin_bit_cast(short8, H[2 * ks + 1]), BH[2 * ks + 1], acch1, 0, 0, 0);
        }

        // --- prefetch x(t+1) (compiler-visible; waits auto-inserted) ---
        if (t + 1 < T_LEN) {
            int tn = t + 1, st = tn;
            if (dir) st = (tn < LA) ? (LA - 1 - tn) : tn;
            const bf16* xp = xb + ((size_t)st * BATCH + b0 + uu) * HDIM + q * 8;
#pragma unroll
            for (int ks = 0; ks < 16; ++ks)
                A[ks] = *reinterpret_cast<const u32x4*>(xp + ks * 32);
        }

        // --- gate exchange (wave w -> cols w*16..w*16+15) ---
        {
            int col = w * 16 + uu;
#pragma unroll
            for (int r = 0; r < 4; ++r)
                Gl[q * 4 + r][col] = accx[r] + acch0[r] + acch1[r];
        }
        __syncthreads();   // B2

        // --- pointwise LSTM cell ---
        float gi = Gl[bb][cu];
        float gf = Gl[bb][16 + cu];
        float gg = Gl[bb][32 + cu];
        float go = Gl[bb][48 + cu];
        float iv = fsigmoid(gi), fv = fsigmoid(gf), gv = ftanh(gg), ov = fsigmoid(go);
        c_reg = fv * c_reg + iv * gv;
        float hv = ov * ftanh(c_reg);

        // --- h store: packed dwords; fast path = ATOMIC EXCHANGE (executes
        //     at the XCD L2 -> vmcnt retirement == L2 visibility) ---
        bf16* hd = hbuf + (size_t)((p ^ 1) * 2 + dir) * (BATCH * HDIM);
        unsigned lo = (unsigned)bfbits(hv);
        unsigned hi = (unsigned)__shfl_down((int)lo, 1);
        if ((cu & 1) == 0) {
            unsigned* hw = reinterpret_cast<unsigned*>(hd) + ((b_glob * HDIM + u0 + cu) >> 1);
            unsigned val = lo | (hi << 16);
            if (fast) {
                unsigned old = __hip_atomic_exchange(hw, val, __ATOMIC_RELAXED,
                                                     __HIP_MEMORY_SCOPE_WORKGROUP);
                (void)old;
            } else {
                __hip_atomic_store(hw, val, __ATOMIC_RELAXED, __HIP_MEMORY_SCOPE_SYSTEM);
            }
        }
        int tout = t;
        if (dir) tout = (t < Lb) ? (Lb - 1 - t) : t;
        out[((size_t)tout * BATCH + b_glob) * (2 * HDIM) + dir * HDIM + u0 + cu] = hv;

        __syncthreads();   // B3: all waves' stores/atomics drained (vmcnt(0))
        if (tid == 0) {
            unsigned tok = (unsigned)(t + 1);
            if (fast) {
                unsigned old = __hip_atomic_exchange(flagw, tok, __ATOMIC_RELAXED,
                                                     __HIP_MEMORY_SCOPE_WORKGROUP);
                (void)old;
            } else {
                __hip_atomic_store(flagw, tok, __ATOMIC_RELAXED, __HIP_MEMORY_SCOPE_SYSTEM);
            }
        }
    }
}

// ---------------------------------------------------------------------------
extern "C" void kernel_launch(void* const* d_in, const int* in_sizes, int n_in,
                              void* d_out, int out_size, void* d_ws, size_t ws_size,
                              hipStream_t stream)
{
    const float* x     = (const float*)d_in[0];
    const int* lengths = (const int*)d_in[1];
    const float* h0f   = (const float*)d_in[2];
    const float* c0f   = (const float*)d_in[3];
    const float* h0b   = (const float*)d_in[4];
    const float* c0b   = (const float*)d_in[5];
    const float* wihf  = (const float*)d_in[6];
    const float* whhf  = (const float*)d_in[7];
    const float* bihf  = (const float*)d_in[8];
    const float* bhhf  = (const float*)d_in[9];
    const float* wihb  = (const float*)d_in[10];
    const float* whhb  = (const float*)d_in[11];
    const float* bihb  = (const float*)d_in[12];
    const float* bhhb  = (const float*)d_in[13];
    float* out = (float*)d_out;

    char* ws = (char*)d_ws;
    bf16*     wih_bf = (bf16*)(ws);                        // 4 MB
    bf16*     whh_bf = (bf16*)(ws + (4u << 20));           // 4 MB
    float*    bias   = (float*)(ws + (8u << 20));          // 16 KB
    bf16*     hbuf   = (bf16*)(ws + (9u << 20));           // 256 KB (scratch only)
    unsigned* flags  = (unsigned*)(ws + (11u << 20));      // 1 KB
    unsigned* xcdarr = (unsigned*)(ws + (11u << 20) + 4096);
    unsigned* abortw = (unsigned*)(ws + (11u << 20) + 8192);
    bf16*     xb     = (bf16*)(ws + (16u << 20));          // 64 MB

    conv_weights<<<dim3(2 * G4 * HDIM / 256), dim3(256), 0, stream>>>(
        wihf, whhf, bihf, bhhf, wihb, whhb, bihb, bhhb, wih_bf, whh_bf, bias);
    conv_x<<<dim3((T_LEN * BATCH * HDIM / 8) / 256), dim3(256), 0, stream>>>(x, xb);
    init_sync<<<dim3(1), dim3(256), 0, stream>>>(flags, xcdarr, abortw);

    lstm_full<<<dim3(256), dim3(256), 0, stream>>>(
        xb, wih_bf, whh_bf, bias, lengths, h0f, c0f, h0b, c0b,
        hbuf, out, flags, xcdarr, abortw);
}